// Round 2
// baseline (432.863 us; speedup 1.0000x reference)
//
#include <hip/hip_runtime.h>
#include <hip/hip_bf16.h>
#include <stdint.h>

#define S_LEN 2048
#define NB 4
#define NH 16
#define HD 64
#define E_DIM 1024

typedef __attribute__((ext_vector_type(8))) short s16x8;
typedef __attribute__((ext_vector_type(4))) float f32x4;
typedef __attribute__((ext_vector_type(16))) float f32x16;
typedef __attribute__((ext_vector_type(4))) int i32x4;

__device__ __forceinline__ short f2bf(float f) {
  union { float f; uint32_t u; } x; x.f = f;
  uint32_t r = (x.u + 0x7FFF + ((x.u >> 16) & 1)) >> 16;
  return (short)r;
}

__device__ __forceinline__ int cvtpk_bf16(float lo, float hi) {
  int r;
  asm("v_cvt_pk_bf16_f32 %0, %1, %2" : "=v"(r) : "v"(lo), "v"(hi));
  return r;
}

__device__ __forceinline__ void glds16(const void* g, void* l) {
  __builtin_amdgcn_global_load_lds(
      (const __attribute__((address_space(1))) unsigned int*)g,
      (__attribute__((address_space(3))) unsigned int*)l, 16, 0, 0);
}

// ---------------- fp32 -> bf16 convert (vectorized) ----------------
__global__ void cvt_f32_bf16(const float* __restrict__ src, short* __restrict__ dst, int n4) {
  int i = blockIdx.x * blockDim.x + threadIdx.x;
  if (i < n4) {
    float4 v = reinterpret_cast<const float4*>(src)[i];
    short4 o;
    o.x = f2bf(v.x); o.y = f2bf(v.y); o.z = f2bf(v.z); o.w = f2bf(v.w);
    reinterpret_cast<short4*>(dst)[i] = o;
  }
}

// ---------------- padding mask -> per-batch lengths ----------------
__global__ void compute_lengths(const unsigned char* __restrict__ mask, int* __restrict__ lengths) {
  int b = blockIdx.x;
  unsigned char b0 = mask[0], b1 = mask[1];
  int mode = (b0 == 0) ? 2 : ((b1 != 0) ? 0 : 1);
  int cnt = 0;
  for (int s = threadIdx.x; s < S_LEN; s += blockDim.x) {
    bool v;
    if (mode == 0)      v = mask[(size_t)b * S_LEN + s] != 0;
    else if (mode == 1) v = reinterpret_cast<const int*>(mask)[(size_t)b * S_LEN + s] != 0;
    else                v = reinterpret_cast<const float*>(mask)[(size_t)b * S_LEN + s] != 0.f;
    cnt += v ? 1 : 0;
  }
  __shared__ int red[256];
  red[threadIdx.x] = cnt;
  __syncthreads();
  for (int o = 128; o > 0; o >>= 1) {
    if (threadIdx.x < o) red[threadIdx.x] += red[threadIdx.x + o];
    __syncthreads();
  }
  if (threadIdx.x == 0) lengths[b] = red[0];
}

// ---------------- NT bf16 GEMM (m97 structure: global_load_lds, 128x128, BK=32) ----------------
// MODE 0: Cout[m*N+n] = acc + bias[n]  (fp32)
// MODE 1: scatter to Q (scaled 0.125*log2e), K [B,H,S,D], V transposed [B,H,D,S] (bf16)
template <int MODE>
__launch_bounds__(256, 3)
__global__ void gemm_nt(const short* __restrict__ A, const short* __restrict__ Bw,
                        const float* __restrict__ bias, float* __restrict__ Cout,
                        short* __restrict__ Qo, short* __restrict__ Ko, short* __restrict__ Vo,
                        int M, int N, int K) {
  __shared__ short Al[128 * 32];
  __shared__ short Bl[128 * 32];
  const int tid = threadIdx.x;
  const int lane = tid & 63;
  const int w = tid >> 6;
  const int wm = w >> 1, wn = w & 1;
  const int l15 = lane & 15, l4 = lane >> 4;
  const int bm = blockIdx.y, bn = blockIdx.x;

  // staging: wave w covers rows [w*32, w*32+32) in two gload_lds of 16 rows each.
  const int srow = w * 32 + (lane >> 2);
  const int scol = (lane & 3) * 8;
  const short* Ag = A + (size_t)(bm * 128 + srow) * K + scol;
  const short* Bg = Bw + (size_t)(bn * 128 + srow) * K + scol;
  const size_t row16 = (size_t)16 * K;
  short* Asm = &Al[(w * 32) * 32];  // wave-uniform; HW adds lane*16B
  short* Bsm = &Bl[(w * 32) * 32];

  f32x4 acc[4][4];
#pragma unroll
  for (int i = 0; i < 4; ++i)
#pragma unroll
    for (int j = 0; j < 4; ++j) acc[i][j] = (f32x4){0.f, 0.f, 0.f, 0.f};

  const int NT = K / 32;
  for (int kt = 0; kt < NT; ++kt) {
    const short* a0 = Ag + kt * 32;
    const short* b0 = Bg + kt * 32;
    glds16(a0, Asm);
    glds16(a0 + row16, Asm + 16 * 32);
    glds16(b0, Bsm);
    glds16(b0 + row16, Bsm + 16 * 32);
    __syncthreads();  // compiler drains vmcnt before barrier
    s16x8 af[4], bf[4];
#pragma unroll
    for (int mi = 0; mi < 4; ++mi)
      af[mi] = *reinterpret_cast<const s16x8*>(&Al[(wm * 64 + mi * 16 + l15) * 32 + l4 * 8]);
#pragma unroll
    for (int nj = 0; nj < 4; ++nj)
      bf[nj] = *reinterpret_cast<const s16x8*>(&Bl[(wn * 64 + nj * 16 + l15) * 32 + l4 * 8]);
#pragma unroll
    for (int mi = 0; mi < 4; ++mi)
#pragma unroll
      for (int nj = 0; nj < 4; ++nj)
        acc[mi][nj] = __builtin_amdgcn_mfma_f32_16x16x32_bf16(af[mi], bf[nj], acc[mi][nj], 0, 0, 0);
    __syncthreads();
  }

#pragma unroll
  for (int mi = 0; mi < 4; ++mi) {
#pragma unroll
    for (int nj = 0; nj < 4; ++nj) {
#pragma unroll
      for (int r = 0; r < 4; ++r) {
        int m = bm * 128 + wm * 64 + mi * 16 + l4 * 4 + r;
        int n = bn * 128 + wn * 64 + nj * 16 + l15;
        float v = acc[mi][nj][r] + bias[n];
        if (MODE == 0) {
          Cout[(size_t)m * N + n] = v;
        } else {
          int b = m >> 11, s = m & 2047;
          int which = n >> 10, e = n & 1023;
          int h = e >> 6, d = e & 63;
          if (which == 0)  // fold D^-0.5 * log2(e) so attention uses exp2
            Qo[(((size_t)(b * NH + h)) * S_LEN + s) * HD + d] = f2bf(v * 0.180336880111f);
          else if (which == 1)
            Ko[(((size_t)(b * NH + h)) * S_LEN + s) * HD + d] = f2bf(v);
          else
            Vo[(((size_t)(b * NH + h)) * HD + d) * S_LEN + s] = f2bf(v);  // V transposed
        }
      }
    }
  }
}

// ---------------- flash attention: swapped QK^T, 32x32 MFMA, no LDS ----------------
// Per wave: 32 q-rows, full key loop in 32-key tiles. Lane holds q-row (lane&31);
// lane and lane^32 split the 32 keys of a tile (16 S-regs each).
__launch_bounds__(256, 4)
__global__ void attn_fwd(const short* __restrict__ Q, const short* __restrict__ K,
                         const short* __restrict__ Vt, short* __restrict__ ctx,
                         const int* __restrict__ lengths) {
  const int tid = threadIdx.x;
  const int lane = tid & 63, w = tid >> 6;
  const int l31 = lane & 31, hi = lane >> 5;
  const int qt = blockIdx.x & 15;  // S/128
  const int bh = blockIdx.x >> 4;
  const int b = bh >> 4;
  const int len = lengths[b];

  const size_t bhS = (size_t)bh * S_LEN;
  const int qrow = qt * 128 + w * 32 + l31;
  const short* Qb = Q + (bhS + qrow) * HD + hi * 8;
  s16x8 qf0 = *reinterpret_cast<const s16x8*>(Qb);
  s16x8 qf1 = *reinterpret_cast<const s16x8*>(Qb + 16);
  s16x8 qf2 = *reinterpret_cast<const s16x8*>(Qb + 32);
  s16x8 qf3 = *reinterpret_cast<const s16x8*>(Qb + 48);

  const short* Kb = K + bhS * HD + hi * 8;                            // [S][64]
  const short* V0 = Vt + bhS * HD + (size_t)l31 * S_LEN + hi * 8;     // d = l31
  const short* V1 = V0 + (size_t)32 * S_LEN;                          // d = 32+l31

  f32x16 o0, o1;
#pragma unroll
  for (int r = 0; r < 16; ++r) { o0[r] = 0.f; o1[r] = 0.f; }
  float m_run = -3e38f, l_run = 0.f;

  auto tile = [&](int kt, int mrem) {
    const short* Kt = Kb + (size_t)(kt * 32 + l31) * HD;
    s16x8 kf0 = *reinterpret_cast<const s16x8*>(Kt);
    s16x8 kf1 = *reinterpret_cast<const s16x8*>(Kt + 16);
    s16x8 kf2 = *reinterpret_cast<const s16x8*>(Kt + 32);
    s16x8 kf3 = *reinterpret_cast<const s16x8*>(Kt + 48);
    f32x16 sa;
#pragma unroll
    for (int r = 0; r < 16; ++r) sa[r] = 0.f;
    __builtin_amdgcn_s_setprio(1);
    sa = __builtin_amdgcn_mfma_f32_32x32x16_bf16(kf0, qf0, sa, 0, 0, 0);
    sa = __builtin_amdgcn_mfma_f32_32x32x16_bf16(kf1, qf1, sa, 0, 0, 0);
    sa = __builtin_amdgcn_mfma_f32_32x32x16_bf16(kf2, qf2, sa, 0, 0, 0);
    sa = __builtin_amdgcn_mfma_f32_32x32x16_bf16(kf3, qf3, sa, 0, 0, 0);
    __builtin_amdgcn_s_setprio(0);
    if (mrem < 32) {  // only the last tile
#pragma unroll
      for (int r = 0; r < 16; ++r) {
        int off = (r & 3) + 8 * (r >> 2) + 4 * hi;
        if (off >= mrem) sa[r] = -3e38f;
      }
    }
    // row max (in-lane tree + one cross-half combine)
    float t0 = fmaxf(sa[0], sa[1]), t1 = fmaxf(sa[2], sa[3]);
    float t2 = fmaxf(sa[4], sa[5]), t3 = fmaxf(sa[6], sa[7]);
    float t4 = fmaxf(sa[8], sa[9]), t5 = fmaxf(sa[10], sa[11]);
    float t6 = fmaxf(sa[12], sa[13]), t7 = fmaxf(sa[14], sa[15]);
    t0 = fmaxf(t0, t1); t2 = fmaxf(t2, t3); t4 = fmaxf(t4, t5); t6 = fmaxf(t6, t7);
    float mx = fmaxf(fmaxf(t0, t2), fmaxf(t4, t6));
    mx = fmaxf(mx, __shfl_xor(mx, 32));
    if (!__all(mx <= m_run + 8.f)) {  // defer-max (T13)
      float mnew = fmaxf(m_run, mx);
      float al = exp2f(m_run - mnew);
#pragma unroll
      for (int r = 0; r < 16; ++r) { o0[r] *= al; o1[r] *= al; }
      l_run *= al;
      m_run = mnew;
    }
#pragma unroll
    for (int r = 0; r < 16; ++r) sa[r] = exp2f(sa[r] - m_run);
    float u0 = (sa[0] + sa[1]) + (sa[2] + sa[3]);
    float u1 = (sa[4] + sa[5]) + (sa[6] + sa[7]);
    float u2 = (sa[8] + sa[9]) + (sa[10] + sa[11]);
    float u3 = (sa[12] + sa[13]) + (sa[14] + sa[15]);
    float ssum = (u0 + u1) + (u2 + u3);
    ssum += __shfl_xor(ssum, 32);
    l_run += ssum;
    // P^T -> bf16 B-fragments: pack pairs, exchange halves with partner lane (^32)
    int A0 = cvtpk_bf16(sa[0], sa[1]),   B0 = cvtpk_bf16(sa[2], sa[3]);
    int A1 = cvtpk_bf16(sa[4], sa[5]),   B1 = cvtpk_bf16(sa[6], sa[7]);
    int A2 = cvtpk_bf16(sa[8], sa[9]),   B2 = cvtpk_bf16(sa[10], sa[11]);
    int A3 = cvtpk_bf16(sa[12], sa[13]), B3 = cvtpk_bf16(sa[14], sa[15]);
    int sA0 = __shfl_xor(A0, 32), sB0 = __shfl_xor(B0, 32);
    int sA1 = __shfl_xor(A1, 32), sB1 = __shfl_xor(B1, 32);
    int sA2 = __shfl_xor(A2, 32), sB2 = __shfl_xor(B2, 32);
    int sA3 = __shfl_xor(A3, 32), sB3 = __shfl_xor(B3, 32);
    union { i32x4 i; s16x8 h; } u0f, u1f;
    u0f.i = hi ? (i32x4){sA1, sB1, A1, B1} : (i32x4){A0, B0, sA0, sB0};  // keys ks=0 (0..15)
    u1f.i = hi ? (i32x4){sA3, sB3, A3, B3} : (i32x4){A2, B2, sA2, sB2};  // keys ks=1 (16..31)
    // PV: O^T[d][q] += V^T[d][k] * P^T[k][q], V read straight from global (L2-hot)
    const short* Vk0 = V0 + kt * 32;
    const short* Vk1 = V1 + kt * 32;
    s16x8 v00 = *reinterpret_cast<const s16x8*>(Vk0);
    s16x8 v01 = *reinterpret_cast<const s16x8*>(Vk0 + 16);
    s16x8 v10 = *reinterpret_cast<const s16x8*>(Vk1);
    s16x8 v11 = *reinterpret_cast<const s16x8*>(Vk1 + 16);
    __builtin_amdgcn_s_setprio(1);
    o0 = __builtin_amdgcn_mfma_f32_32x32x16_bf16(v00, u0f.h, o0, 0, 0, 0);
    o0 = __builtin_amdgcn_mfma_f32_32x32x16_bf16(v01, u1f.h, o0, 0, 0, 0);
    o1 = __builtin_amdgcn_mfma_f32_32x32x16_bf16(v10, u0f.h, o1, 0, 0, 0);
    o1 = __builtin_amdgcn_mfma_f32_32x32x16_bf16(v11, u1f.h, o1, 0, 0, 0);
    __builtin_amdgcn_s_setprio(0);
  };

  const int nfull = len >> 5;
  const int rem = len & 31;
  for (int kt = 0; kt < nfull; ++kt) tile(kt, 32);
  if (rem) tile(nfull, rem);

  const float inv = 1.f / l_run;
  const int h = bh & 15;
  const size_t base = ((size_t)b * S_LEN + qrow) * E_DIM + h * HD + 4 * hi;
#pragma unroll
  for (int rq = 0; rq < 4; ++rq) {
    short4 a, c;
    a.x = f2bf(o0[4 * rq + 0] * inv); a.y = f2bf(o0[4 * rq + 1] * inv);
    a.z = f2bf(o0[4 * rq + 2] * inv); a.w = f2bf(o0[4 * rq + 3] * inv);
    *reinterpret_cast<short4*>(&ctx[base + 8 * rq]) = a;
    c.x = f2bf(o1[4 * rq + 0] * inv); c.y = f2bf(o1[4 * rq + 1] * inv);
    c.z = f2bf(o1[4 * rq + 2] * inv); c.w = f2bf(o1[4 * rq + 3] * inv);
    *reinterpret_cast<short4*>(&ctx[base + 32 + 8 * rq]) = c;
  }
}

// ---------------- launch ----------------
extern "C" void kernel_launch(void* const* d_in, const int* in_sizes, int n_in,
                              void* d_out, int out_size, void* d_ws, size_t ws_size,
                              hipStream_t stream) {
  const float* x = (const float*)d_in[0];
  const unsigned char* mask = (const unsigned char*)d_in[1];
  const float* qkv_w = (const float*)d_in[2];
  const float* qkv_b = (const float*)d_in[3];
  const float* proj_w = (const float*)d_in[4];
  const float* proj_b = (const float*)d_in[5];
  float* out = (float*)d_out;

  const size_t SZ_X = (size_t)NB * S_LEN * E_DIM;
  short* xb = (short*)d_ws;
  short* wqb = xb + SZ_X;
  short* wpb = wqb + (size_t)3 * E_DIM * E_DIM;
  short* Qs = wpb + (size_t)E_DIM * E_DIM;
  short* Ks = Qs + SZ_X;
  short* Vts = Ks + SZ_X;
  short* ctx = Vts + SZ_X;
  int* lens = (int*)(ctx + SZ_X);

  cvt_f32_bf16<<<(int)(SZ_X / 4 / 256), 256, 0, stream>>>(x, xb, (int)(SZ_X / 4));
  cvt_f32_bf16<<<3 * E_DIM * E_DIM / 4 / 256, 256, 0, stream>>>(qkv_w, wqb, 3 * E_DIM * E_DIM / 4);
  cvt_f32_bf16<<<E_DIM * E_DIM / 4 / 256, 256, 0, stream>>>(proj_w, wpb, E_DIM * E_DIM / 4);
  compute_lengths<<<NB, 256, 0, stream>>>(mask, lens);

  dim3 g1(3 * E_DIM / 128, NB * S_LEN / 128);  // (24, 64)
  gemm_nt<1><<<g1, 256, 0, stream>>>(xb, wqb, qkv_b, nullptr, Qs, Ks, Vts,
                                     NB * S_LEN, 3 * E_DIM, E_DIM);

  attn_fwd<<<NB * NH * (S_LEN / 128), 256, 0, stream>>>(Qs, Ks, Vts, ctx, lens);

  dim3 g2(E_DIM / 128, NB * S_LEN / 128);  // (8, 64)
  gemm_nt<0><<<g2, 256, 0, stream>>>(ctx, wpb, proj_b, out, nullptr, nullptr, nullptr,
                                     NB * S_LEN, E_DIM, E_DIM);
}